// Round 2
// baseline (875.271 us; speedup 1.0000x reference)
//
#include <hip/hip_runtime.h>
#include <hip/hip_bf16.h>

#define DIMK 64
#define NREL 16

__global__ void zero_denom_kernel(float* __restrict__ denom, int n) {
    int i = blockIdx.x * blockDim.x + threadIdx.x;
    if (i < n) denom[i] = 0.0f;
}

__device__ __forceinline__ float tanh_fast(float x) {
    float e = __expf(2.0f * x);
    return 1.0f - 2.0f / (e + 1.0f);
}

// lane k's partial (t,h) for one edge: t = sum_d es[d]*w[d], h = sum_d ed[d]*w[d]
__device__ __forceinline__ void matvec2(const float4* __restrict__ es4,
                                        const float4* __restrict__ ed4,
                                        const float* __restrict__ w,
                                        float& tout, float& hout) {
    float t0 = 0.f, t1 = 0.f, t2 = 0.f, t3 = 0.f;
    float h0 = 0.f, h1 = 0.f, h2 = 0.f, h3 = 0.f;
    #pragma unroll
    for (int i = 0; i < DIMK / 4; ++i) {
        float4 a = es4[i];   // wave-uniform address -> broadcast load
        float4 b = ed4[i];
        t0 = fmaf(a.x, w[4 * i + 0], t0);
        t1 = fmaf(a.y, w[4 * i + 1], t1);
        t2 = fmaf(a.z, w[4 * i + 2], t2);
        t3 = fmaf(a.w, w[4 * i + 3], t3);
        h0 = fmaf(b.x, w[4 * i + 0], h0);
        h1 = fmaf(b.y, w[4 * i + 1], h1);
        h2 = fmaf(b.z, w[4 * i + 2], h2);
        h3 = fmaf(b.w, w[4 * i + 3], h3);
    }
    tout = (t0 + t1) + (t2 + t3);
    hout = (h0 + h1) + (h2 + h3);
}

__device__ __forceinline__ float wave_sum(float p) {
    #pragma unroll
    for (int off = 32; off > 0; off >>= 1) p += __shfl_xor(p, off);
    return p;
}

// grid: 16 types x NCHUNK chunks. Block (type,c) scans chunk c; each wave pins
// W[type]'s column `lane` in 64 VGPRs (launch_bounds(256,2) grants the budget).
// Matched edges processed 2 at a time (uniform control flow) for ILP.
__global__ __launch_bounds__(256, 2)
void edge_att_kernel(const float* __restrict__ emb,
                     const float* __restrict__ rel,
                     const float* __restrict__ WR,
                     const int* __restrict__ esrc,
                     const int* __restrict__ edst,
                     const int* __restrict__ etype,
                     float* __restrict__ exbuf,   // aliases d_out; holds exp(att)
                     float* __restrict__ denom,
                     int E, int chunkSize) {
    const int type = blockIdx.x & 15;
    const int c    = blockIdx.x >> 4;
    const int lane = threadIdx.x & 63;
    const int wid  = threadIdx.x >> 6;

    long base0 = (long)c * (long)chunkSize;
    long cend  = base0 + chunkSize;
    if (cend > E) cend = E;
    if (base0 >= cend) return;

    int per = (chunkSize + 3) >> 2;   // 4 waves per block
    long wbeg = base0 + (long)wid * per;
    long wend = wbeg + per;
    if (wend > cend) wend = cend;
    if (wbeg >= wend) return;         // wid is wave-uniform -> uniform exit

    // W column for this type: w[d] = WR[type][d][lane]  (coalesced across lanes)
    float w[DIMK];
    const float* Wt = WR + (size_t)type * DIMK * DIMK;
    #pragma unroll
    for (int d = 0; d < DIMK; ++d) w[d] = Wt[d * DIMK + lane];
    const float rk = rel[type * DIMK + lane];

    for (long s0 = wbeg; s0 < wend; s0 += 64) {
        long e = s0 + lane;
        int ty = -1, sv = 0, dv = 0;
        if (e < wend) {
            ty = etype[e];
            sv = esrc[e];
            dv = edst[e];
        }
        unsigned long long m = __ballot(ty == type);
        while (m) {
            int b0 = __builtin_ctzll(m);          // uniform
            m &= m - 1;
            if (m) {                              // paired: 2 edges this iter
                int b1 = __builtin_ctzll(m);
                m &= m - 1;
                int sn0 = __builtin_amdgcn_readlane(sv, b0);
                int dn0 = __builtin_amdgcn_readlane(dv, b0);
                int sn1 = __builtin_amdgcn_readlane(sv, b1);
                int dn1 = __builtin_amdgcn_readlane(dv, b1);
                float t0, h0, t1, h1;
                matvec2((const float4*)(emb + (size_t)sn0 * DIMK),
                        (const float4*)(emb + (size_t)dn0 * DIMK), w, t0, h0);
                matvec2((const float4*)(emb + (size_t)sn1 * DIMK),
                        (const float4*)(emb + (size_t)dn1 * DIMK), w, t1, h1);
                float p0 = wave_sum(t0 * tanh_fast(h0 + rk));
                float p1 = wave_sum(t1 * tanh_fast(h1 + rk));
                if (lane == 0) {
                    float ex0 = __expf(p0);
                    float ex1 = __expf(p1);
                    exbuf[s0 + b0] = ex0;
                    exbuf[s0 + b1] = ex1;
                    atomicAdd(&denom[dn0], ex0);
                    atomicAdd(&denom[dn1], ex1);
                }
            } else {                              // single tail edge
                int sn0 = __builtin_amdgcn_readlane(sv, b0);
                int dn0 = __builtin_amdgcn_readlane(dv, b0);
                float t0, h0;
                matvec2((const float4*)(emb + (size_t)sn0 * DIMK),
                        (const float4*)(emb + (size_t)dn0 * DIMK), w, t0, h0);
                float p0 = wave_sum(t0 * tanh_fast(h0 + rk));
                if (lane == 0) {
                    float ex0 = __expf(p0);
                    exbuf[s0 + b0] = ex0;
                    atomicAdd(&denom[dn0], ex0);
                }
            }
        }
    }
}

__global__ void normalize_kernel(float* __restrict__ out,
                                 const float* __restrict__ denom,
                                 const int* __restrict__ edst, int E) {
    int e = blockIdx.x * blockDim.x + threadIdx.x;
    if (e < E) out[e] = out[e] / denom[edst[e]];
}

extern "C" void kernel_launch(void* const* d_in, const int* in_sizes, int n_in,
                              void* d_out, int out_size, void* d_ws, size_t ws_size,
                              hipStream_t stream) {
    const float* emb  = (const float*)d_in[0];   // [n_nodes, 64]
    const float* rel  = (const float*)d_in[1];   // [16, 64]
    const float* WR   = (const float*)d_in[2];   // [16, 64, 64]
    const int*   esrc = (const int*)d_in[3];     // [E]
    const int*   edst = (const int*)d_in[4];     // [E]
    const int*   ety  = (const int*)d_in[5];     // [E]

    const int E       = in_sizes[3];
    const int n_nodes = in_sizes[0] / DIMK;

    float* out   = (float*)d_out;   // [E]
    float* denom = (float*)d_ws;    // [n_nodes] scratch

    zero_denom_kernel<<<(n_nodes + 255) / 256, 256, 0, stream>>>(denom, n_nodes);

    const int NCHUNK = 256;
    int chunk = (E + NCHUNK - 1) / NCHUNK;
    edge_att_kernel<<<16 * NCHUNK, 256, 0, stream>>>(emb, rel, WR, esrc, edst, ety,
                                                     out, denom, E, chunk);

    normalize_kernel<<<(E + 255) / 256, 256, 0, stream>>>(out, denom, edst, E);
}

// Round 3
// 395.563 us; speedup vs baseline: 2.2127x; 2.2127x over previous
//
#include <hip/hip_runtime.h>
#include <hip/hip_bf16.h>

#define D64 64
#define NREL 16

typedef __attribute__((ext_vector_type(8))) short bf16x8;
typedef __attribute__((ext_vector_type(4))) float f32x4;

__device__ __forceinline__ float tanh_fast(float x) {
    float e = __expf(2.0f * x);
    return 1.0f - 2.0f / (e + 1.0f);
}

__device__ __forceinline__ short f2b(float x) {
    __hip_bfloat16 h = __float2bfloat16(x);
    return *reinterpret_cast<short*>(&h);
}

__global__ void zero_denom_kernel(float* __restrict__ denom, int n) {
    int i = blockIdx.x * blockDim.x + threadIdx.x;
    if (i < n) denom[i] = 0.0f;
}

// Cast W (transposed to [r][col][d]) and rel to bf16.
__global__ void prep_kernel(const float* __restrict__ WR, const float* __restrict__ rel,
                            unsigned short* __restrict__ Wt, unsigned short* __restrict__ relb) {
    int i = blockIdx.x * blockDim.x + threadIdx.x;
    if (i < NREL * D64 * D64) {
        int r = i >> 12, rem = i & 4095, col = rem >> 6, d = rem & 63;
        Wt[i] = (unsigned short)f2b(WR[(r << 12) + (d << 6) + col]);
    }
    if (i < NREL * D64) {
        relb[i] = (unsigned short)f2b(rel[i]);
    }
}

// trans[r][n][k] = sum_d emb[n][d] * W[r][d][k], bf16 output, f32 accumulate.
// Block = 256 thr = 4 waves; wave handles 16 nodes x all 64 k x all 16 r.
// MFMA 16x16x32 layouts (m89/m91-verified):
//   A[m=lane&15][k=(lane>>4)*8+j], B[k=(lane>>4)*8+j][n=lane&15],
//   C/D: col=lane&15, row=(lane>>4)*4+reg.
__global__ __launch_bounds__(256)
void trans_gemm_kernel(const float* __restrict__ emb,
                       const unsigned short* __restrict__ Wt,  // [r][col][d] bf16
                       unsigned short* __restrict__ trans,     // [r][n][k] bf16
                       int n_nodes) {
    const int lane = threadIdx.x & 63;
    const int wid  = threadIdx.x >> 6;
    const int row  = lane & 15;   // M index within tile
    const int quad = lane >> 4;   // selects k-subrange
    const int nodebase = blockIdx.x * 64 + wid * 16;

    // A fragments for this wave's 16 nodes (f32 -> bf16 inline)
    int arow = nodebase + row;
    if (arow >= n_nodes) arow = n_nodes - 1;   // clamped; stores are guarded
    const float* ap = emb + (size_t)arow * D64 + quad * 8;
    bf16x8 afrag[2];
    #pragma unroll
    for (int ks = 0; ks < 2; ++ks) {
        float4 a0 = *(const float4*)(ap + ks * 32);
        float4 a1 = *(const float4*)(ap + ks * 32 + 4);
        afrag[ks][0] = f2b(a0.x); afrag[ks][1] = f2b(a0.y);
        afrag[ks][2] = f2b(a0.z); afrag[ks][3] = f2b(a0.w);
        afrag[ks][4] = f2b(a1.x); afrag[ks][5] = f2b(a1.y);
        afrag[ks][6] = f2b(a1.z); afrag[ks][7] = f2b(a1.w);
    }

    for (int r = 0; r < NREL; ++r) {
        const unsigned short* w = Wt + (r << 12);   // [col][d]
        f32x4 acc[4];
        #pragma unroll
        for (int nt = 0; nt < 4; ++nt) {
            // B[k][n]: n = nt*16+row (stored as Wt row), k = ks*32 + quad*8 + j
            const unsigned short* wb = w + (size_t)(nt * 16 + row) * D64 + quad * 8;
            bf16x8 b0 = *(const bf16x8*)(wb);
            bf16x8 b1 = *(const bf16x8*)(wb + 32);
            f32x4 c = {0.f, 0.f, 0.f, 0.f};
            c = __builtin_amdgcn_mfma_f32_16x16x32_bf16(afrag[0], b0, c, 0, 0, 0);
            c = __builtin_amdgcn_mfma_f32_16x16x32_bf16(afrag[1], b1, c, 0, 0, 0);
            acc[nt] = c;
        }
        size_t outbase = ((size_t)r * n_nodes + nodebase) * D64;
        #pragma unroll
        for (int reg = 0; reg < 4; ++reg) {
            int nrow = quad * 4 + reg;                 // node within tile
            if (nodebase + nrow < n_nodes) {
                size_t rb = outbase + (size_t)nrow * D64;
                #pragma unroll
                for (int nt = 0; nt < 4; ++nt)
                    trans[rb + nt * 16 + row] = (unsigned short)f2b(acc[nt][reg]);
            }
        }
    }
}

__device__ __forceinline__ float2 b2f2(unsigned u) {
    float lo = __uint_as_float(u << 16);
    float hi = __uint_as_float(u & 0xffff0000u);
    return make_float2(lo, hi);
}

__device__ __forceinline__ float pair_term(unsigned s, unsigned h, unsigned r) {
    float2 sf = b2f2(s), hf = b2f2(h), rf = b2f2(r);
    return sf.x * tanh_fast(hf.x + rf.x) + sf.y * tanh_fast(hf.y + rf.y);
}

// One thread per edge: att = sum_k t_k * tanh(h_k + rel_k); ex = exp(att).
__global__ __launch_bounds__(256)
void edge_kernel(const unsigned short* __restrict__ trans,
                 const unsigned short* __restrict__ relb,
                 const int* __restrict__ esrc, const int* __restrict__ edst,
                 const int* __restrict__ etype,
                 float* __restrict__ out, float* __restrict__ denom,
                 int E, int n_nodes) {
    int e = blockIdx.x * 256 + threadIdx.x;
    if (e >= E) return;
    int t = etype[e], s = esrc[e], d = edst[e];
    const uint4* ps = (const uint4*)(trans + ((size_t)t * n_nodes + s) * D64);
    const uint4* ph = (const uint4*)(trans + ((size_t)t * n_nodes + d) * D64);
    const uint4* pr = (const uint4*)(relb + t * D64);
    float acc = 0.f;
    #pragma unroll
    for (int i = 0; i < 8; ++i) {
        uint4 us = ps[i], uh = ph[i], ur = pr[i];
        acc += pair_term(us.x, uh.x, ur.x);
        acc += pair_term(us.y, uh.y, ur.y);
        acc += pair_term(us.z, uh.z, ur.z);
        acc += pair_term(us.w, uh.w, ur.w);
    }
    float ex = __expf(acc);   // att is O(0.5): exp safe without max-shift
    out[e] = ex;
    atomicAdd(&denom[d], ex);
}

__global__ void normalize_kernel(float* __restrict__ out,
                                 const float* __restrict__ denom,
                                 const int* __restrict__ edst, int E) {
    int e = blockIdx.x * blockDim.x + threadIdx.x;
    if (e < E) out[e] = out[e] / denom[edst[e]];
}

// ---------------- fallback (R1 structure) if ws is too small ----------------
__global__ __launch_bounds__(256)
void edge_att_fallback(const float* __restrict__ emb, const float* __restrict__ rel,
                       const float* __restrict__ WR, const int* __restrict__ esrc,
                       const int* __restrict__ edst, const int* __restrict__ etype,
                       float* __restrict__ exbuf, float* __restrict__ denom,
                       int E, int chunkSize) {
    const int type = blockIdx.x & 15;
    const int c    = blockIdx.x >> 4;
    const int lane = threadIdx.x & 63;
    const int wid  = threadIdx.x >> 6;
    long base0 = (long)c * (long)chunkSize;
    long cend  = base0 + chunkSize;
    if (cend > E) cend = E;
    if (base0 >= cend) return;
    int per = (chunkSize + 3) >> 2;
    long wbeg = base0 + (long)wid * per;
    long wend = wbeg + per;
    if (wend > cend) wend = cend;
    if (wbeg >= wend) return;
    float w[D64];
    const float* Wt = WR + (size_t)type * D64 * D64;
    #pragma unroll
    for (int d = 0; d < D64; ++d) w[d] = Wt[d * D64 + lane];
    const float rk = rel[type * D64 + lane];
    for (long s0 = wbeg; s0 < wend; s0 += 64) {
        long e = s0 + lane;
        int ty = -1, sv = 0, dv = 0;
        if (e < wend) { ty = etype[e]; sv = esrc[e]; dv = edst[e]; }
        unsigned long long m = __ballot(ty == type);
        while (m) {
            int b = __builtin_ctzll(m);
            m &= m - 1;
            int sn = __builtin_amdgcn_readlane(sv, b);
            int dn = __builtin_amdgcn_readlane(dv, b);
            const float4* es4 = (const float4*)(emb + (size_t)sn * D64);
            const float4* ed4 = (const float4*)(emb + (size_t)dn * D64);
            float t0 = 0.f, t1 = 0.f, t2 = 0.f, t3 = 0.f;
            float h0 = 0.f, h1 = 0.f, h2 = 0.f, h3 = 0.f;
            #pragma unroll
            for (int i = 0; i < D64 / 4; ++i) {
                float4 a = es4[i]; float4 b4 = ed4[i];
                t0 = fmaf(a.x, w[4*i+0], t0); t1 = fmaf(a.y, w[4*i+1], t1);
                t2 = fmaf(a.z, w[4*i+2], t2); t3 = fmaf(a.w, w[4*i+3], t3);
                h0 = fmaf(b4.x, w[4*i+0], h0); h1 = fmaf(b4.y, w[4*i+1], h1);
                h2 = fmaf(b4.z, w[4*i+2], h2); h3 = fmaf(b4.w, w[4*i+3], h3);
            }
            float t = (t0 + t1) + (t2 + t3);
            float h = (h0 + h1) + (h2 + h3);
            float p = t * tanh_fast(h + rk);
            #pragma unroll
            for (int off = 32; off > 0; off >>= 1) p += __shfl_xor(p, off);
            if (lane == 0) {
                float ex = __expf(p);
                exbuf[s0 + b] = ex;
                atomicAdd(&denom[dn], ex);
            }
        }
    }
}
// ---------------------------------------------------------------------------

extern "C" void kernel_launch(void* const* d_in, const int* in_sizes, int n_in,
                              void* d_out, int out_size, void* d_ws, size_t ws_size,
                              hipStream_t stream) {
    const float* emb  = (const float*)d_in[0];   // [n_nodes, 64]
    const float* rel  = (const float*)d_in[1];   // [16, 64]
    const float* WR   = (const float*)d_in[2];   // [16, 64, 64]
    const int*   esrc = (const int*)d_in[3];     // [E]
    const int*   edst = (const int*)d_in[4];     // [E]
    const int*   ety  = (const int*)d_in[5];     // [E]

    const int E       = in_sizes[3];
    const int n_nodes = in_sizes[0] / D64;
    float* out = (float*)d_out;

    // workspace carve (256-B aligned)
    size_t transB = (size_t)NREL * n_nodes * D64 * sizeof(unsigned short);
    size_t off_trans = 0;
    size_t off_wt    = (off_trans + transB + 255) & ~(size_t)255;
    size_t off_rel   = (off_wt + (size_t)NREL * D64 * D64 * 2 + 255) & ~(size_t)255;
    size_t off_den   = (off_rel + (size_t)NREL * D64 * 2 + 255) & ~(size_t)255;
    size_t need      = off_den + (size_t)n_nodes * sizeof(float);

    if (ws_size >= need) {
        unsigned short* trans = (unsigned short*)((char*)d_ws + off_trans);
        unsigned short* Wt    = (unsigned short*)((char*)d_ws + off_wt);
        unsigned short* relb  = (unsigned short*)((char*)d_ws + off_rel);
        float*          denom = (float*)((char*)d_ws + off_den);

        prep_kernel<<<(NREL * D64 * D64 + 255) / 256, 256, 0, stream>>>(WR, rel, Wt, relb);
        zero_denom_kernel<<<(n_nodes + 255) / 256, 256, 0, stream>>>(denom, n_nodes);
        trans_gemm_kernel<<<(n_nodes + 63) / 64, 256, 0, stream>>>(emb, Wt, trans, n_nodes);
        edge_kernel<<<(E + 255) / 256, 256, 0, stream>>>(trans, relb, esrc, edst, ety,
                                                         out, denom, E, n_nodes);
        normalize_kernel<<<(E + 255) / 256, 256, 0, stream>>>(out, denom, edst, E);
    } else {
        float* denom = (float*)d_ws;   // [n_nodes]
        zero_denom_kernel<<<(n_nodes + 255) / 256, 256, 0, stream>>>(denom, n_nodes);
        const int NCHUNK = 256;
        int chunk = (E + NCHUNK - 1) / NCHUNK;
        edge_att_fallback<<<16 * NCHUNK, 256, 0, stream>>>(emb, rel, WR, esrc, edst, ety,
                                                           out, denom, E, chunk);
        normalize_kernel<<<(E + 255) / 256, 256, 0, stream>>>(out, denom, edst, E);
    }
}

// Round 4
// 334.524 us; speedup vs baseline: 2.6165x; 1.1825x over previous
//
#include <hip/hip_runtime.h>
#include <hip/hip_bf16.h>

#define D64 64
#define NREL 16
#define SCALE 32.0f
#define INV_SCALE 0.03125f

typedef __attribute__((ext_vector_type(8))) short bf16x8;
typedef __attribute__((ext_vector_type(4))) float f32x4;
typedef __attribute__((ext_vector_type(2))) float f32x2;

__device__ __forceinline__ float tanh_fast(float x) {
    float e = __expf(2.0f * x);
    return 1.0f - 2.0f / (e + 1.0f);
}

__device__ __forceinline__ short f2b(float x) {
    __hip_bfloat16 h = __float2bfloat16(x);
    return *reinterpret_cast<short*>(&h);
}

__global__ void zero_denom_kernel(float* __restrict__ denom, int n) {
    int i = blockIdx.x * blockDim.x + threadIdx.x;
    if (i < n) denom[i] = 0.0f;
}

// Wt[r][col][d] = bf16(WR[r][d][col]);  relp[t][kp] = rel[t][(kp&3)*16 + (kp>>2)]
// (relp uses the same k-permutation the trans rows are stored in)
__global__ void prep_kernel(const float* __restrict__ WR, const float* __restrict__ rel,
                            unsigned short* __restrict__ Wt, float* __restrict__ relp) {
    int i = blockIdx.x * blockDim.x + threadIdx.x;
    if (i < NREL * D64 * D64) {
        int r = i >> 12, rem = i & 4095, col = rem >> 6, d = rem & 63;
        Wt[i] = (unsigned short)f2b(WR[(r << 12) + (d << 6) + col]);
    }
    if (i < NREL * D64) {
        int t = i >> 6, kp = i & 63;
        relp[i] = rel[t * D64 + (kp & 3) * 16 + (kp >> 2)];
    }
}

// trans[r][n][kp] = fp8(SCALE * sum_d emb[n][d]*W[r][d][k]),  kp = col*4 + nt
// (permutation is harmless: edge reduction over k is permutation-invariant).
// Row = 64 fp8 = 16 dwords; lane col stores 1 dword per reg -> fully coalesced.
// MFMA 16x16x32 layouts (R3-verified): A[m=lane&15][k=quad*8+j],
// B[k=quad*8+j][n=lane&15], C/D col=lane&15 row=quad*4+reg.
__global__ __launch_bounds__(256)
void trans_gemm_kernel(const float* __restrict__ emb,
                       const unsigned short* __restrict__ Wt,  // [r][col][d] bf16
                       unsigned* __restrict__ trans,           // [r][n][16] dwords (fp8x4)
                       int n_nodes) {
    const int lane = threadIdx.x & 63;
    const int wid  = threadIdx.x >> 6;
    const int col  = lane & 15;
    const int quad = lane >> 4;
    const int nodebase = blockIdx.x * 64 + wid * 16;

    int arow = nodebase + col;                   // m index for A
    if (arow >= n_nodes) arow = n_nodes - 1;     // clamped; stores guarded
    const float* ap = emb + (size_t)arow * D64 + quad * 8;
    bf16x8 afrag[2];
    #pragma unroll
    for (int ks = 0; ks < 2; ++ks) {
        float4 a0 = *(const float4*)(ap + ks * 32);
        float4 a1 = *(const float4*)(ap + ks * 32 + 4);
        afrag[ks][0] = f2b(a0.x); afrag[ks][1] = f2b(a0.y);
        afrag[ks][2] = f2b(a0.z); afrag[ks][3] = f2b(a0.w);
        afrag[ks][4] = f2b(a1.x); afrag[ks][5] = f2b(a1.y);
        afrag[ks][6] = f2b(a1.z); afrag[ks][7] = f2b(a1.w);
    }

    for (int r = 0; r < NREL; ++r) {
        const unsigned short* w = Wt + (r << 12);   // [col][d]
        f32x4 acc[4];
        #pragma unroll
        for (int nt = 0; nt < 4; ++nt) {
            const unsigned short* wb = w + (size_t)(nt * 16 + col) * D64 + quad * 8;
            bf16x8 b0 = *(const bf16x8*)(wb);
            bf16x8 b1 = *(const bf16x8*)(wb + 32);
            f32x4 c = {0.f, 0.f, 0.f, 0.f};
            c = __builtin_amdgcn_mfma_f32_16x16x32_bf16(afrag[0], b0, c, 0, 0, 0);
            c = __builtin_amdgcn_mfma_f32_16x16x32_bf16(afrag[1], b1, c, 0, 0, 0);
            acc[nt] = c;
        }
        #pragma unroll
        for (int reg = 0; reg < 4; ++reg) {
            int nrow = quad * 4 + reg;
            int node = nodebase + nrow;
            if (node < n_nodes) {
                unsigned pk = __builtin_amdgcn_cvt_pk_fp8_f32(
                    acc[0][reg] * SCALE, acc[1][reg] * SCALE, 0, false);
                pk = __builtin_amdgcn_cvt_pk_fp8_f32(
                    acc[2][reg] * SCALE, acc[3][reg] * SCALE, pk, true);
                trans[((size_t)r * n_nodes + node) * 16 + col] = pk;
            }
        }
    }
}

// 4 fp8 terms: acc += t * tanh(h*INV_SCALE + rel)   (t,h pre-scaled by SCALE)
__device__ __forceinline__ void term4(unsigned ut, unsigned uh, float4 r, float& acc) {
    f32x2 tlo = __builtin_amdgcn_cvt_pk_f32_fp8(ut, false);
    f32x2 thi = __builtin_amdgcn_cvt_pk_f32_fp8(ut, true);
    f32x2 hlo = __builtin_amdgcn_cvt_pk_f32_fp8(uh, false);
    f32x2 hhi = __builtin_amdgcn_cvt_pk_f32_fp8(uh, true);
    acc += tlo[0] * tanh_fast(fmaf(hlo[0], INV_SCALE, r.x));
    acc += tlo[1] * tanh_fast(fmaf(hlo[1], INV_SCALE, r.y));
    acc += thi[0] * tanh_fast(fmaf(hhi[0], INV_SCALE, r.z));
    acc += thi[1] * tanh_fast(fmaf(hhi[1], INV_SCALE, r.w));
}

// One thread per edge; rows are 64-B fp8, gathered as 4 uint4 each.
__global__ __launch_bounds__(256)
void edge_kernel(const unsigned* __restrict__ trans,
                 const float* __restrict__ relp,
                 const int* __restrict__ esrc, const int* __restrict__ edst,
                 const int* __restrict__ etype,
                 float* __restrict__ out, float* __restrict__ denom,
                 int E, int n_nodes) {
    int e = blockIdx.x * 256 + threadIdx.x;
    if (e >= E) return;
    int t = etype[e], s = esrc[e], d = edst[e];
    const uint4*  pt = (const uint4*)(trans + ((size_t)t * n_nodes + s) * 16);
    const uint4*  ph = (const uint4*)(trans + ((size_t)t * n_nodes + d) * 16);
    const float4* pr = (const float4*)(relp + t * D64);
    float acc = 0.f;
    #pragma unroll
    for (int c4 = 0; c4 < 4; ++c4) {
        uint4 ut = pt[c4];
        uint4 uh = ph[c4];
        term4(ut.x, uh.x, pr[c4 * 4 + 0], acc);
        term4(ut.y, uh.y, pr[c4 * 4 + 1], acc);
        term4(ut.z, uh.z, pr[c4 * 4 + 2], acc);
        term4(ut.w, uh.w, pr[c4 * 4 + 3], acc);
    }
    float ex = __expf(acc * INV_SCALE);   // att is O(0.1): exp safe w/o max-shift
    out[e] = ex;
    atomicAdd(&denom[d], ex);
}

__global__ void normalize_kernel(float* __restrict__ out,
                                 const float* __restrict__ denom,
                                 const int* __restrict__ edst, int E) {
    int e = blockIdx.x * blockDim.x + threadIdx.x;
    if (e < E) out[e] = out[e] / denom[edst[e]];
}

// ---------------- fallback (R1 structure) if ws is too small ----------------
__global__ __launch_bounds__(256)
void edge_att_fallback(const float* __restrict__ emb, const float* __restrict__ rel,
                       const float* __restrict__ WR, const int* __restrict__ esrc,
                       const int* __restrict__ edst, const int* __restrict__ etype,
                       float* __restrict__ exbuf, float* __restrict__ denom,
                       int E, int chunkSize) {
    const int type = blockIdx.x & 15;
    const int c    = blockIdx.x >> 4;
    const int lane = threadIdx.x & 63;
    const int wid  = threadIdx.x >> 6;
    long base0 = (long)c * (long)chunkSize;
    long cend  = base0 + chunkSize;
    if (cend > E) cend = E;
    if (base0 >= cend) return;
    int per = (chunkSize + 3) >> 2;
    long wbeg = base0 + (long)wid * per;
    long wend = wbeg + per;
    if (wend > cend) wend = cend;
    if (wbeg >= wend) return;
    float w[D64];
    const float* Wt = WR + (size_t)type * D64 * D64;
    #pragma unroll
    for (int d = 0; d < D64; ++d) w[d] = Wt[d * D64 + lane];
    const float rk = rel[type * D64 + lane];
    for (long s0 = wbeg; s0 < wend; s0 += 64) {
        long e = s0 + lane;
        int ty = -1, sv = 0, dv = 0;
        if (e < wend) { ty = etype[e]; sv = esrc[e]; dv = edst[e]; }
        unsigned long long m = __ballot(ty == type);
        while (m) {
            int b = __builtin_ctzll(m);
            m &= m - 1;
            int sn = __builtin_amdgcn_readlane(sv, b);
            int dn = __builtin_amdgcn_readlane(dv, b);
            const float4* es4 = (const float4*)(emb + (size_t)sn * D64);
            const float4* ed4 = (const float4*)(emb + (size_t)dn * D64);
            float t0 = 0.f, t1 = 0.f, t2 = 0.f, t3 = 0.f;
            float h0 = 0.f, h1 = 0.f, h2 = 0.f, h3 = 0.f;
            #pragma unroll
            for (int i = 0; i < D64 / 4; ++i) {
                float4 a = es4[i]; float4 b4 = ed4[i];
                t0 = fmaf(a.x, w[4*i+0], t0); t1 = fmaf(a.y, w[4*i+1], t1);
                t2 = fmaf(a.z, w[4*i+2], t2); t3 = fmaf(a.w, w[4*i+3], t3);
                h0 = fmaf(b4.x, w[4*i+0], h0); h1 = fmaf(b4.y, w[4*i+1], h1);
                h2 = fmaf(b4.z, w[4*i+2], h2); h3 = fmaf(b4.w, w[4*i+3], h3);
            }
            float t = (t0 + t1) + (t2 + t3);
            float h = (h0 + h1) + (h2 + h3);
            float p = t * tanh_fast(h + rk);
            #pragma unroll
            for (int off = 32; off > 0; off >>= 1) p += __shfl_xor(p, off);
            if (lane == 0) {
                float ex = __expf(p);
                exbuf[s0 + b] = ex;
                atomicAdd(&denom[dn], ex);
            }
        }
    }
}
// ---------------------------------------------------------------------------

extern "C" void kernel_launch(void* const* d_in, const int* in_sizes, int n_in,
                              void* d_out, int out_size, void* d_ws, size_t ws_size,
                              hipStream_t stream) {
    const float* emb  = (const float*)d_in[0];   // [n_nodes, 64]
    const float* rel  = (const float*)d_in[1];   // [16, 64]
    const float* WR   = (const float*)d_in[2];   // [16, 64, 64]
    const int*   esrc = (const int*)d_in[3];     // [E]
    const int*   edst = (const int*)d_in[4];     // [E]
    const int*   ety  = (const int*)d_in[5];     // [E]

    const int E       = in_sizes[3];
    const int n_nodes = in_sizes[0] / D64;
    float* out = (float*)d_out;

    // workspace carve (256-B aligned)
    size_t transB = (size_t)NREL * n_nodes * D64;            // fp8 bytes
    size_t off_trans = 0;
    size_t off_wt    = (off_trans + transB + 255) & ~(size_t)255;
    size_t off_rel   = (off_wt + (size_t)NREL * D64 * D64 * 2 + 255) & ~(size_t)255;
    size_t off_den   = (off_rel + (size_t)NREL * D64 * 4 + 255) & ~(size_t)255;
    size_t need      = off_den + (size_t)n_nodes * sizeof(float);

    if (ws_size >= need) {
        unsigned*       trans = (unsigned*)((char*)d_ws + off_trans);
        unsigned short* Wt    = (unsigned short*)((char*)d_ws + off_wt);
        float*          relp  = (float*)((char*)d_ws + off_rel);
        float*          denom = (float*)((char*)d_ws + off_den);

        prep_kernel<<<(NREL * D64 * D64 + 255) / 256, 256, 0, stream>>>(WR, rel, Wt, relp);
        zero_denom_kernel<<<(n_nodes + 255) / 256, 256, 0, stream>>>(denom, n_nodes);
        trans_gemm_kernel<<<(n_nodes + 63) / 64, 256, 0, stream>>>(emb, Wt, trans, n_nodes);
        edge_kernel<<<(E + 255) / 256, 256, 0, stream>>>(trans, relp, esrc, edst, ety,
                                                         out, denom, E, n_nodes);
        normalize_kernel<<<(E + 255) / 256, 256, 0, stream>>>(out, denom, edst, E);
    } else {
        float* denom = (float*)d_ws;   // [n_nodes]
        zero_denom_kernel<<<(n_nodes + 255) / 256, 256, 0, stream>>>(denom, n_nodes);
        const int NCHUNK = 256;
        int chunk = (E + NCHUNK - 1) / NCHUNK;
        edge_att_fallback<<<16 * NCHUNK, 256, 0, stream>>>(emb, rel, WR, esrc, edst, ety,
                                                           out, denom, E, chunk);
        normalize_kernel<<<(E + 255) / 256, 256, 0, stream>>>(out, denom, edst, E);
    }
}

// Round 6
// 256.560 us; speedup vs baseline: 3.4116x; 1.3039x over previous
//
#include <hip/hip_runtime.h>
#include <hip/hip_bf16.h>

#define D64 64
#define NREL 16
#define SCALE 32.0f
#define INV_SCALE 0.03125f

typedef __attribute__((ext_vector_type(8))) short bf16x8;
typedef __attribute__((ext_vector_type(4))) float f32x4;
typedef __attribute__((ext_vector_type(2))) float f32x2;

__device__ __forceinline__ float tanh_fast(float x) {
    float e = __expf(2.0f * x);
    return 1.0f - 2.0f / (e + 1.0f);
}

__device__ __forceinline__ unsigned short f2b(float x) {
    __hip_bfloat16 h = __float2bfloat16(x);
    return *reinterpret_cast<unsigned short*>(&h);
}

__global__ void zero_denom_kernel(float* __restrict__ denom, int n) {
    int i = blockIdx.x * blockDim.x + threadIdx.x;
    if (i < n) denom[i] = 0.0f;
}

// R4-structure prep: Wt[r][c][d] = bf16(WR[r][d][c]); relp k-permuted to match
// the role-swapped trans store layout: kp = q*16 + m*4 + g <-> k = m*16 + q*4 + g.
__global__ void prep_kernel(const float* __restrict__ WR, const float* __restrict__ rel,
                            unsigned short* __restrict__ Wt, float* __restrict__ relp) {
    int i = blockIdx.x * blockDim.x + threadIdx.x;
    if (i < NREL * D64 * D64) {
        int r = i >> 12, rem = i & 4095, c = rem >> 6, d = rem & 63;
        Wt[i] = f2b(WR[(r << 12) + (d << 6) + c]);
    }
    if (i < NREL * D64) {
        int t = i >> 6, kp = i & 63;
        int q = kp >> 4, m = (kp >> 2) & 3, g = kp & 3;
        relp[i] = rel[t * D64 + m * 16 + q * 4 + g];
    }
}

// Role-swapped MFMA: D[m=k_out][n=node]; A = Wt rows (A[m=lane&15][d=quad*8+j]),
// B = emb rows (f32 from d_in, inline bf16 cvt; B[d=quad*8+j][n=lane&15]).
// Wave owns 64 nodes (4 tiles); B-frags pinned in regs across all 16 relations
// -> Wt re-read 240 MB total (vs 960 MB for the 16-node layout).
// Lane (col,quad) packs its 16 k-values of node `col` into one dwordx4 store:
// 16 lanes x 16 B = contiguous 1 KB per (r, node-tile).
// Stored kp = quad*16 + mt*4 + reg  <->  true k = mt*16 + quad*4 + reg.
__global__ __launch_bounds__(256)
void trans_gemm_kernel(const float* __restrict__ emb,
                       const unsigned short* __restrict__ Wt,
                       uint4* __restrict__ trans,   // [r][node] rows of 4 x uint4
                       int n_nodes) {
    const int lane = threadIdx.x & 63;
    const int wid  = threadIdx.x >> 6;
    const int col  = lane & 15;
    const int quad = lane >> 4;
    const int nodebase = blockIdx.x * 256 + wid * 64;

    bf16x8 bfr[4][2];
    int nds[4];
    #pragma unroll
    for (int j = 0; j < 4; ++j) {
        int node = nodebase + j * 16 + col;
        nds[j] = node;
        int cn = node < n_nodes ? node : n_nodes - 1;
        const float* bp = emb + (size_t)cn * D64 + quad * 8;
        #pragma unroll
        for (int ks = 0; ks < 2; ++ks) {
            float4 v0 = *(const float4*)(bp + ks * 32);
            float4 v1 = *(const float4*)(bp + ks * 32 + 4);
            bfr[j][ks][0] = (short)f2b(v0.x); bfr[j][ks][1] = (short)f2b(v0.y);
            bfr[j][ks][2] = (short)f2b(v0.z); bfr[j][ks][3] = (short)f2b(v0.w);
            bfr[j][ks][4] = (short)f2b(v1.x); bfr[j][ks][5] = (short)f2b(v1.y);
            bfr[j][ks][6] = (short)f2b(v1.z); bfr[j][ks][7] = (short)f2b(v1.w);
        }
    }

    #pragma unroll 1
    for (int r = 0; r < NREL; ++r) {
        const unsigned short* w = Wt + (r << 12);
        f32x4 acc[4][4];   // [mt][j]
        #pragma unroll
        for (int mt = 0; mt < 4; ++mt) {
            const unsigned short* ap = w + (size_t)(mt * 16 + col) * D64 + quad * 8;
            bf16x8 a0 = *(const bf16x8*)ap;
            bf16x8 a1 = *(const bf16x8*)(ap + 32);
            #pragma unroll
            for (int j = 0; j < 4; ++j) {
                f32x4 c = {0.f, 0.f, 0.f, 0.f};
                c = __builtin_amdgcn_mfma_f32_16x16x32_bf16(a0, bfr[j][0], c, 0, 0, 0);
                c = __builtin_amdgcn_mfma_f32_16x16x32_bf16(a1, bfr[j][1], c, 0, 0, 0);
                acc[mt][j] = c;
            }
        }
        #pragma unroll
        for (int j = 0; j < 4; ++j) {
            if (nds[j] < n_nodes) {
                uint4 pk;
                unsigned p;
                p = __builtin_amdgcn_cvt_pk_fp8_f32(acc[0][j][0] * SCALE, acc[0][j][1] * SCALE, 0, false);
                p = __builtin_amdgcn_cvt_pk_fp8_f32(acc[0][j][2] * SCALE, acc[0][j][3] * SCALE, p, true);
                pk.x = p;
                p = __builtin_amdgcn_cvt_pk_fp8_f32(acc[1][j][0] * SCALE, acc[1][j][1] * SCALE, 0, false);
                p = __builtin_amdgcn_cvt_pk_fp8_f32(acc[1][j][2] * SCALE, acc[1][j][3] * SCALE, p, true);
                pk.y = p;
                p = __builtin_amdgcn_cvt_pk_fp8_f32(acc[2][j][0] * SCALE, acc[2][j][1] * SCALE, 0, false);
                p = __builtin_amdgcn_cvt_pk_fp8_f32(acc[2][j][2] * SCALE, acc[2][j][3] * SCALE, p, true);
                pk.z = p;
                p = __builtin_amdgcn_cvt_pk_fp8_f32(acc[3][j][0] * SCALE, acc[3][j][1] * SCALE, 0, false);
                p = __builtin_amdgcn_cvt_pk_fp8_f32(acc[3][j][2] * SCALE, acc[3][j][3] * SCALE, p, true);
                pk.w = p;
                trans[((size_t)r * n_nodes + nds[j]) * 4 + quad] = pk;
            }
        }
    }
}

// 4 fp8 terms: acc += t * tanh(h*INV_SCALE + rel)   (t,h pre-scaled by SCALE)
__device__ __forceinline__ void term4(unsigned ut, unsigned uh, float4 r, float& acc) {
    f32x2 tlo = __builtin_amdgcn_cvt_pk_f32_fp8(ut, false);
    f32x2 thi = __builtin_amdgcn_cvt_pk_f32_fp8(ut, true);
    f32x2 hlo = __builtin_amdgcn_cvt_pk_f32_fp8(uh, false);
    f32x2 hhi = __builtin_amdgcn_cvt_pk_f32_fp8(uh, true);
    acc += tlo[0] * tanh_fast(fmaf(hlo[0], INV_SCALE, r.x));
    acc += tlo[1] * tanh_fast(fmaf(hlo[1], INV_SCALE, r.y));
    acc += thi[0] * tanh_fast(fmaf(hhi[0], INV_SCALE, r.z));
    acc += thi[1] * tanh_fast(fmaf(hhi[1], INV_SCALE, r.w));
}

// One thread per edge; rows are 64-B fp8, gathered as 4 uint4 each.
__global__ __launch_bounds__(256)
void edge_kernel(const unsigned* __restrict__ trans,
                 const float* __restrict__ relp,
                 const int* __restrict__ esrc, const int* __restrict__ edst,
                 const int* __restrict__ etype,
                 float* __restrict__ out, float* __restrict__ denom,
                 int E, int n_nodes) {
    int e = blockIdx.x * 256 + threadIdx.x;
    if (e >= E) return;
    int t = etype[e], s = esrc[e], d = edst[e];
    const uint4*  pt = (const uint4*)(trans + ((size_t)t * n_nodes + s) * 16);
    const uint4*  ph = (const uint4*)(trans + ((size_t)t * n_nodes + d) * 16);
    const float4* pr = (const float4*)(relp + t * D64);
    float acc = 0.f;
    #pragma unroll
    for (int c4 = 0; c4 < 4; ++c4) {
        uint4 ut = pt[c4];
        uint4 uh = ph[c4];
        term4(ut.x, uh.x, pr[c4 * 4 + 0], acc);
        term4(ut.y, uh.y, pr[c4 * 4 + 1], acc);
        term4(ut.z, uh.z, pr[c4 * 4 + 2], acc);
        term4(ut.w, uh.w, pr[c4 * 4 + 3], acc);
    }
    float ex = __expf(acc * INV_SCALE);
    out[e] = ex;
    atomicAdd(&denom[d], ex);
}

__global__ void normalize_kernel(float* __restrict__ out,
                                 const float* __restrict__ denom,
                                 const int* __restrict__ edst, int E) {
    int e = blockIdx.x * blockDim.x + threadIdx.x;
    if (e < E) out[e] = out[e] / denom[edst[e]];
}

// ---------------- fallback (R1 structure) if ws is too small ----------------
__global__ __launch_bounds__(256)
void edge_att_fallback(const float* __restrict__ emb, const float* __restrict__ rel,
                       const float* __restrict__ WR, const int* __restrict__ esrc,
                       const int* __restrict__ edst, const int* __restrict__ etype,
                       float* __restrict__ exbuf, float* __restrict__ denom,
                       int E, int chunkSize) {
    const int type = blockIdx.x & 15;
    const int c    = blockIdx.x >> 4;
    const int lane = threadIdx.x & 63;
    const int wid  = threadIdx.x >> 6;
    long base0 = (long)c * (long)chunkSize;
    long cend  = base0 + chunkSize;
    if (cend > E) cend = E;
    if (base0 >= cend) return;
    int per = (chunkSize + 3) >> 2;
    long wbeg = base0 + (long)wid * per;
    long wend = wbeg + per;
    if (wend > cend) wend = cend;
    if (wbeg >= wend) return;
    float w[D64];
    const float* Wt = WR + (size_t)type * D64 * D64;
    #pragma unroll
    for (int d = 0; d < D64; ++d) w[d] = Wt[d * D64 + lane];
    const float rk = rel[type * D64 + lane];
    for (long s0 = wbeg; s0 < wend; s0 += 64) {
        long e = s0 + lane;
        int ty = -1, sv = 0, dv = 0;
        if (e < wend) { ty = etype[e]; sv = esrc[e]; dv = edst[e]; }
        unsigned long long m = __ballot(ty == type);
        while (m) {
            int b = __builtin_ctzll(m);
            m &= m - 1;
            int sn = __builtin_amdgcn_readlane(sv, b);
            int dn = __builtin_amdgcn_readlane(dv, b);
            const float4* es4 = (const float4*)(emb + (size_t)sn * D64);
            const float4* ed4 = (const float4*)(emb + (size_t)dn * D64);
            float t0 = 0.f, t1 = 0.f, t2 = 0.f, t3 = 0.f;
            float h0 = 0.f, h1 = 0.f, h2 = 0.f, h3 = 0.f;
            #pragma unroll
            for (int i = 0; i < D64 / 4; ++i) {
                float4 a = es4[i]; float4 b4 = ed4[i];
                t0 = fmaf(a.x, w[4*i+0], t0); t1 = fmaf(a.y, w[4*i+1], t1);
                t2 = fmaf(a.z, w[4*i+2], t2); t3 = fmaf(a.w, w[4*i+3], t3);
                h0 = fmaf(b4.x, w[4*i+0], h0); h1 = fmaf(b4.y, w[4*i+1], h1);
                h2 = fmaf(b4.z, w[4*i+2], h2); h3 = fmaf(b4.w, w[4*i+3], h3);
            }
            float t = (t0 + t1) + (t2 + t3);
            float h = (h0 + h1) + (h2 + h3);
            float p = t * tanh_fast(h + rk);
            #pragma unroll
            for (int off = 32; off > 0; off >>= 1) p += __shfl_xor(p, off);
            if (lane == 0) {
                float ex = __expf(p);
                exbuf[s0 + b] = ex;
                atomicAdd(&denom[dn], ex);
            }
        }
    }
}
// ---------------------------------------------------------------------------

extern "C" void kernel_launch(void* const* d_in, const int* in_sizes, int n_in,
                              void* d_out, int out_size, void* d_ws, size_t ws_size,
                              hipStream_t stream) {
    const float* emb  = (const float*)d_in[0];   // [n_nodes, 64]
    const float* rel  = (const float*)d_in[1];   // [16, 64]
    const float* WR   = (const float*)d_in[2];   // [16, 64, 64]
    const int*   esrc = (const int*)d_in[3];     // [E]
    const int*   edst = (const int*)d_in[4];     // [E]
    const int*   ety  = (const int*)d_in[5];     // [E]

    const int E       = in_sizes[3];
    const int n_nodes = in_sizes[0] / D64;
    float* out = (float*)d_out;

    // workspace carve (256-B aligned) — same as the R4 (passing) layout
    size_t transB = (size_t)NREL * n_nodes * D64;            // fp8 bytes
    size_t off_trans = 0;
    size_t off_wt    = (off_trans + transB + 255) & ~(size_t)255;
    size_t off_rel   = (off_wt + (size_t)NREL * D64 * D64 * 2 + 255) & ~(size_t)255;
    size_t off_den   = (off_rel + (size_t)NREL * D64 * 4 + 255) & ~(size_t)255;
    size_t need      = off_den + (size_t)n_nodes * sizeof(float);

    if (ws_size >= need) {
        uint4*          trans = (uint4*)((char*)d_ws + off_trans);
        unsigned short* Wt    = (unsigned short*)((char*)d_ws + off_wt);
        float*          relp  = (float*)((char*)d_ws + off_rel);
        float*          denom = (float*)((char*)d_ws + off_den);

        prep_kernel<<<(NREL * D64 * D64 + 255) / 256, 256, 0, stream>>>(WR, rel, Wt, relp);
        zero_denom_kernel<<<(n_nodes + 255) / 256, 256, 0, stream>>>(denom, n_nodes);
        trans_gemm_kernel<<<(n_nodes + 255) / 256, 256, 0, stream>>>(emb, Wt, trans, n_nodes);
        edge_kernel<<<(E + 255) / 256, 256, 0, stream>>>((const unsigned*)trans, relp,
                                                         esrc, edst, ety,
                                                         out, denom, E, n_nodes);
        normalize_kernel<<<(E + 255) / 256, 256, 0, stream>>>(out, denom, edst, E);
    } else {
        float* denom = (float*)d_ws;   // [n_nodes]
        zero_denom_kernel<<<(n_nodes + 255) / 256, 256, 0, stream>>>(denom, n_nodes);
        const int NCHUNK = 256;
        int chunk = (E + NCHUNK - 1) / NCHUNK;
        edge_att_fallback<<<16 * NCHUNK, 256, 0, stream>>>(emb, rel, WR, esrc, edst, ety,
                                                           out, denom, E, chunk);
        normalize_kernel<<<(E + 255) / 256, 256, 0, stream>>>(out, denom, edst, E);
    }
}